// Round 6
// baseline (423.363 us; speedup 1.0000x reference)
//
#include <hip/hip_runtime.h>
#include <math.h>

// Problem constants
#define EMBED   128
#define DMODEL  256   // 2*EMBED
#define DINNER  512
#define HIDN    512
#define NBK     200
#define BQ      1024
#define FEW     5
#define PAD_IDX 200000
#define LN_EPS  1e-5f
#define NTILES  7

#define EMB_ELEMS 25600128   // 200001 * 128
#define EMB_THREADS (EMB_ELEMS / 8)
#define EMB_BLOCKS ((EMB_THREADS + 255) / 256)

typedef short          s16x8  __attribute__((ext_vector_type(8)));
typedef float          f32x4  __attribute__((ext_vector_type(4)));
typedef float          f32x16 __attribute__((ext_vector_type(16)));
typedef unsigned int   u32;
typedef unsigned short u16;

__device__ __forceinline__ float sigmoidf_(float x) { return 1.0f / (1.0f + expf(-x)); }

// float -> bf16 (round-to-nearest-even), raw u16
__device__ __forceinline__ u32 f2bf(float f) {
    u32 u = __builtin_bit_cast(u32, f);
    u += 0x7fffu + ((u >> 16) & 1u);
    return u >> 16;
}
__device__ __forceinline__ s16x8 pack8(float4 a, float4 b) {
    typedef u32 u32x4_ __attribute__((ext_vector_type(4)));
    u32x4_ q;
    q.x = f2bf(a.x) | (f2bf(a.y) << 16);
    q.y = f2bf(a.z) | (f2bf(a.w) << 16);
    q.z = f2bf(b.x) | (f2bf(b.y) << 16);
    q.w = f2bf(b.z) | (f2bf(b.w) << 16);
    return __builtin_bit_cast(s16x8, q);
}

// ---------------------------------------------------------------------------
// Kernel 0: conversion. Blocks [0,512): weights -> bf16 MFMA-B-fragment order
// (wih live rows K=256, whh live rows FULL K=512, p1W, p2W). Blocks [512, +N):
// emb fp32 -> bf16. Frag layout for [N x K] (y = x @ W^T): element (n,k) at
// flat = ((tile*KS + ks)*64 + lane)*8 + j, n = tile*16+(lane&15),
// k = ks*32+(lane>>4)*8+j, KS = K/32.
// ---------------------------------------------------------------------------
__global__ __launch_bounds__(256) void convert_all_kernel(
    const float* __restrict__ W_ih, const float* __restrict__ W_hh,
    const float* __restrict__ p1W,  const float* __restrict__ p2W,
    const float* __restrict__ emb,
    u16* __restrict__ wih_bf, u16* __restrict__ whh_bf,
    u16* __restrict__ p1_bf,  u16* __restrict__ p2_bf,
    u16* __restrict__ emb_bf)
{
    int bid = blockIdx.x;
    if (bid >= 512) {
        size_t gid = (size_t)(bid - 512) * 256 + threadIdx.x;
        if (gid < EMB_THREADS) {
            size_t base = gid * 8;
            float4 x0 = *(const float4*)(emb + base);
            float4 x1 = *(const float4*)(emb + base + 4);
            *(s16x8*)(emb_bf + base) = pack8(x0, x1);
        }
        return;
    }
    int gid = bid * 256 + threadIdx.x;              // 0..131071
    const float* src; u16* dst; int local, stride, KS, liveRemap;
    if (gid < 32768)       { local = gid;          src = W_ih; dst = wih_bf; stride = 256; KS = 8;  liveRemap = 1; }
    else if (gid < 98304)  { local = gid - 32768;  src = W_hh; dst = whh_bf; stride = 512; KS = 16; liveRemap = 1; }
    else if (gid < 114688) { local = gid - 98304;  src = p1W;  dst = p1_bf;  stride = 256; KS = 8;  liveRemap = 0; }
    else                   { local = gid - 114688; src = p2W;  dst = p2_bf;  stride = 512; KS = 16; liveRemap = 0; }
    int lane = local & 63;
    int ts   = local >> 6;
    int ks   = ts & (KS - 1);
    int tile = ts / KS;
    int n  = tile * 16 + (lane & 15);
    int kb = ks * 32 + (lane >> 4) * 8;
    int row = liveRemap ? ((n >> 8) * 512 + (n & 255)) : n;
    const float* sp = src + (size_t)row * stride + kb;
    float4 x0 = *(const float4*)sp;
    float4 x1 = *(const float4*)(sp + 4);
    *(s16x8*)(dst + (size_t)local * 8) = pack8(x0, x1);
}

// ---------------------------------------------------------------------------
// Kernel 1: neighbor encoder, MFMA bf16 32x32x16, cooperative bf16 LDS
// staging at MINIMUM gather-request count (1024 x 16B per tile, no cross-wave
// redundancy -- the r5 direct-gather issued 4096). XOR-swizzled 16B chunks
// (c ^= row&15) make ds_write_b128/ds_read_b128 <=2-way (free). 2-deep
// pipeline: tile i+1's global gathers issue before tile i's MFMA phase.
// ---------------------------------------------------------------------------
template<bool BF>
__global__ __launch_bounds__(256) void neighbor_kernel(
    const int* __restrict__ qlc, const int* __restrict__ qrc,
    const int* __restrict__ slc, const int* __restrict__ src_,
    const float* __restrict__ emb, const u16* __restrict__ emb_bf,
    const float* __restrict__ W,
    const float* __restrict__ wb,  const float* __restrict__ bb,
    float* __restrict__ qn, float* __restrict__ sn)
{
    int b = blockIdx.x;
    const int* conn; float* out; int n; int side;
    if (b < BQ)                { conn = qlc;  n = b;            side = 0; out = qn; }
    else if (b < 2*BQ)         { conn = qrc;  n = b - BQ;       side = 1; out = qn; }
    else if (b < 2*BQ + FEW)   { conn = slc;  n = b - 2*BQ;     side = 0; out = sn; }
    else                       { conn = src_; n = b - 2*BQ-FEW; side = 1; out = sn; }

    int t = threadIdx.x;
    int w = t >> 6, l = t & 63;
    int d0 = w * 32;
    int m31 = l & 31, half = l >> 5;

    __shared__ __align__(16) u16 bs[64 * 128];   // 16 KB: 64 rows x 128 bf16

    // A-frags: afrag[ks] = W[d0+m31][ks*16 + half*8 .. +7] in bf16
    s16x8 afrag[16];
    const float* wrow = W + (d0 + m31) * DMODEL + half * 8;
    #pragma unroll
    for (int ks = 0; ks < 16; ++ks) {
        float4 x0 = *(const float4*)(wrow + ks * 16);
        float4 x1 = *(const float4*)(wrow + ks * 16 + 4);
        afrag[ks] = pack8(x0, x1);
    }

    // Column-validity bitmask (column = m31; identical across waves)
    const int2* crow = (const int2*)(conn + n * NBK * 2);
    u32 vmask = 0;
    #pragma unroll
    for (int nt = 0; nt < NTILES; ++nt) {
        int krow = nt * 32 + m31;
        if (krow < NBK) {
            int2 re = crow[krow];
            if (re.x != PAD_IDX && re.y != PAD_IDX) vmask |= (1u << nt);
        }
    }

    // Gather mapping: thread t -> row gr (0..63: 32 rel + 32 ent), quarter gq
    int gr = t >> 2, gq = t & 3;
    int g_m = gr & 31, g_is_ent = gr >> 5;
    int gsrc[NTILES];
    #pragma unroll
    for (int nt = 0; nt < NTILES; ++nt) {
        int krow = nt * 32 + g_m;
        int rel = PAD_IDX, ent = PAD_IDX;
        if (krow < NBK) { int2 re = crow[krow]; rel = re.x; ent = re.y; }
        int v = (rel != PAD_IDX) && (ent != PAD_IDX);
        gsrc[nt] = v ? (g_is_ent ? ent : rel) : PAD_IDX;   // PAD row = zeros
    }

    // Valid-tile list (identical across all threads)
    int tl[NTILES]; int ntl = 0;
    #pragma unroll
    for (int nt = 0; nt < NTILES; ++nt)
        if (__any((int)((vmask >> nt) & 1u))) tl[ntl++] = nt;

    float vm[16];
    #pragma unroll
    for (int r = 0; r < 16; ++r) vm[r] = -INFINITY;

    // LDS addressing (u16 units), swizzled chunk: row r chunk c at
    // r*128 + ((c ^ (r&15))*8)
    int swl = gr * 128;             // my staging row base
    int rsw_rel = m31 * 128;        // MFMA read rows
    int rsw_ent = (32 + m31) * 128;
    int rx = m31 & 15;              // read-side swizzle key (same for rel/ent)

    s16x8 stg[4];
    auto load_tile = [&](int nt, s16x8* dstv) {
        if (BF) {
            const u16* p = emb_bf + (size_t)gsrc[nt] * EMBED + gq * 32;
            #pragma unroll
            for (int i = 0; i < 4; ++i) dstv[i] = *(const s16x8*)(p + i * 8);
        } else {
            const float* p = emb + (size_t)gsrc[nt] * EMBED + gq * 32;
            #pragma unroll
            for (int i = 0; i < 4; ++i)
                dstv[i] = pack8(*(const float4*)(p + i * 8), *(const float4*)(p + i * 8 + 4));
        }
    };

    if (ntl > 0) load_tile(tl[0], stg);

    for (int i = 0; i < ntl; ++i) {
        int nt = tl[i];
        __syncthreads();   // prior tile's LDS reads complete
        #pragma unroll
        for (int j = 0; j < 4; ++j) {
            int c = gq * 4 + j;
            *(s16x8*)(bs + swl + ((c ^ (gr & 15)) * 8)) = stg[j];
        }
        __syncthreads();   // staged tile visible

        // prefetch next tile (latency hidden behind MFMA below)
        s16x8 stg2[4];
        if (i + 1 < ntl) load_tile(tl[i + 1], stg2);

        // MFMA from LDS
        f32x16 acc = {0.f,0.f,0.f,0.f,0.f,0.f,0.f,0.f,0.f,0.f,0.f,0.f,0.f,0.f,0.f,0.f};
        #pragma unroll
        for (int ks = 0; ks < 8; ++ks) {
            int c = ks * 2 + half;
            s16x8 bfr = *(const s16x8*)(bs + rsw_rel + ((c ^ rx) * 8));
            acc = __builtin_amdgcn_mfma_f32_32x32x16_bf16(afrag[ks], bfr, acc, 0, 0, 0);
        }
        #pragma unroll
        for (int ks = 0; ks < 8; ++ks) {
            int c = ks * 2 + half;
            s16x8 bfr = *(const s16x8*)(bs + rsw_ent + ((c ^ rx) * 8));
            acc = __builtin_amdgcn_mfma_f32_32x32x16_bf16(afrag[8 + ks], bfr, acc, 0, 0, 0);
        }
        int cv = (vmask >> nt) & 1;
        #pragma unroll
        for (int r = 0; r < 16; ++r) {
            float v = cv ? acc[r] : -INFINITY;
            vm[r] = fmaxf(vm[r], v);
        }
        #pragma unroll
        for (int j = 0; j < 4; ++j) stg[j] = stg2[j];
    }

    // Max across 32 columns within each half-wave
    #pragma unroll
    for (int off = 1; off < 32; off <<= 1) {
        #pragma unroll
        for (int r = 0; r < 16; ++r)
            vm[r] = fmaxf(vm[r], __shfl_xor(vm[r], off, 64));
    }

    if (m31 == 0) {
        #pragma unroll
        for (int r = 0; r < 16; ++r) {
            int d = d0 + (r & 3) + 8 * (r >> 2) + 4 * half;
            float p = vm[r] + wb[d] + bb[d];
            p = (p >= 0.f) ? p : 0.1f * p;         // leaky_relu(0.1)
            out[n * DMODEL + side * EMBED + d] = tanhf(p);
        }
    }
}

// ---------------------------------------------------------------------------
// Kernel 2: support encoder via MFMA 16x16x32 bf16. 16 rows/block, 512 thr.
// ---------------------------------------------------------------------------
__global__ __launch_bounds__(512) void support_enc_kernel(
    const float* __restrict__ qn, const float* __restrict__ sn,
    const u16* __restrict__ p1_bf, const float* __restrict__ p1b,
    const u16* __restrict__ p2_bf, const float* __restrict__ p2b,
    const float* __restrict__ lng, const float* __restrict__ lnb,
    float* __restrict__ query_g, float* __restrict__ sup_ln)
{
    __shared__ __align__(16) float xs[16][260];
    __shared__ __align__(16) float hsd[16][516];
    __shared__ __align__(16) float os[16][260];
    int t = threadIdx.x;
    int w = t >> 6, l = t & 63;
    int r0 = blockIdx.x * 16;

    #pragma unroll
    for (int j = 0; j < 8; ++j) {
        int idx = j * 512 + t;
        int r = idx >> 8, cc = idx & 255;
        int row = r0 + r;
        float v = 0.f;
        if (row < BQ + FEW)
            v = (row < BQ) ? qn[(size_t)row * DMODEL + cc] : sn[(size_t)(row - BQ) * DMODEL + cc];
        xs[r][cc] = v;
    }
    __syncthreads();

    int am = l & 15, ak = (l >> 4) * 8;

    s16x8 a1[8];
    #pragma unroll
    for (int ks = 0; ks < 8; ++ks) {
        float4 x0 = *(const float4*)&xs[am][ks * 32 + ak];
        float4 x1 = *(const float4*)&xs[am][ks * 32 + ak + 4];
        a1[ks] = pack8(x0, x1);
    }

    // GEMM1: 32 n-tiles, wave w owns 4w..4w+3
    #pragma unroll
    for (int j = 0; j < 4; ++j) {
        int nt = w * 4 + j;
        f32x4 acc = {0.f, 0.f, 0.f, 0.f};
        const u16* bp = p1_bf + (size_t)nt * 4096 + l * 8;
        #pragma unroll
        for (int ks = 0; ks < 8; ++ks) {
            s16x8 bf = *(const s16x8*)(bp + ks * 512);
            acc = __builtin_amdgcn_mfma_f32_16x16x32_bf16(a1[ks], bf, acc, 0, 0, 0);
        }
        int nn = nt * 16 + (l & 15);
        float bj = p1b[nn];
        #pragma unroll
        for (int reg = 0; reg < 4; ++reg) {
            int m = (l >> 4) * 4 + reg;
            hsd[m][nn] = fmaxf(acc[reg] + bj, 0.f);
        }
    }
    __syncthreads();

    s16x8 a2[16];
    #pragma unroll
    for (int ks = 0; ks < 16; ++ks) {
        float4 x0 = *(const float4*)&hsd[am][ks * 32 + ak];
        float4 x1 = *(const float4*)&hsd[am][ks * 32 + ak + 4];
        a2[ks] = pack8(x0, x1);
    }

    // GEMM2: 16 n-tiles, wave w owns 2w, 2w+1
    #pragma unroll
    for (int j = 0; j < 2; ++j) {
        int nt = w * 2 + j;
        f32x4 acc = {0.f, 0.f, 0.f, 0.f};
        const u16* bp = p2_bf + (size_t)nt * 8192 + l * 8;
        #pragma unroll
        for (int ks = 0; ks < 16; ++ks) {
            s16x8 bf = *(const s16x8*)(bp + ks * 512);
            acc = __builtin_amdgcn_mfma_f32_16x16x32_bf16(a2[ks], bf, acc, 0, 0, 0);
        }
        int nn = nt * 16 + (l & 15);
        float bj = p2b[nn];
        #pragma unroll
        for (int reg = 0; reg < 4; ++reg) {
            int m = (l >> 4) * 4 + reg;
            os[m][nn] = acc[reg] + bj + xs[m][nn];
        }
    }
    __syncthreads();

    // LayerNorm: wave w rows 2w, 2w+1
    for (int j = 0; j < 2; ++j) {
        int m = w * 2 + j;
        float sum = 0.f, sq = 0.f;
        #pragma unroll
        for (int i = 0; i < 4; ++i) {
            float v = os[m][l + 64 * i];
            sum += v; sq += v * v;
        }
        for (int off = 32; off; off >>= 1) {
            sum += __shfl_xor(sum, off, 64);
            sq  += __shfl_xor(sq,  off, 64);
        }
        float mu  = sum * (1.f / DMODEL);
        float var = sq * (1.f / DMODEL) - mu * mu;
        float inv = rsqrtf(var + LN_EPS);
        int row = r0 + m;
        if (row < BQ + FEW) {
            float* outp = (row < BQ) ? (query_g + (size_t)row * DMODEL) : (sup_ln + (size_t)(row - BQ) * DMODEL);
            #pragma unroll
            for (int i = 0; i < 4; ++i) {
                int dd = l + 64 * i;
                outp[dd] = (os[m][dd] - mu) * inv * lng[dd] + lnb[dd];
            }
        }
    }
}

// ---------------------------------------------------------------------------
// Kernel 3: fused LSTM (4 steps) + final dot, MFMA 16x16x32 bf16, K=512.
// h' = [h(256), s(256)] per sample lives in LDS; gates(step>=1) =
// base + biases + h' @ W_hh_live^T (full 512 cols) -- this folds the
// attention term s @ W_hh[:,256:]^T exactly as the reference's h_r concat.
// Block = 16 samples, 512 threads (8 waves); wave w owns gate cols
// [w*32,(w+1)*32): tiles tp = pp*16 + 2w + qt.
// ---------------------------------------------------------------------------
__global__ __launch_bounds__(512) void lstm_mfma_kernel(
    const float* __restrict__ query_g, const float* __restrict__ sup_ln,
    const u16* __restrict__ wih_bf, const u16* __restrict__ whh_bf,
    const float* __restrict__ b_ih, const float* __restrict__ b_hh,
    float* __restrict__ out)
{
    __shared__ __align__(16) float qs[16][260];
    __shared__ __align__(16) float hq[16][516];   // [0,256): h  [256,512): s
    int t = threadIdx.x;
    int w = t >> 6, l = t & 63;
    int n0 = blockIdx.x * 16;

    // load query rows; write s into every row's [256,512) slot
    {
        int cc = t & 255;
        float a = 0.f;
        for (int i = 0; i < FEW; ++i) a += sup_ln[i * DMODEL + cc];
        float svv = a * (1.f / FEW);
        #pragma unroll
        for (int j = 0; j < 8; ++j) {
            int idx = j * 512 + t;
            int r = idx >> 8;
            qs[r][cc] = query_g[(size_t)(n0 + r) * DMODEL + cc];
            hq[r][256 + cc] = svv;
        }
    }
    __syncthreads();

    int am = l & 15, ak = (l >> 4) * 8;

    // base GEMM: query @ W_ih_live^T (K=256)
    f32x4 base[4][2];
    {
        s16x8 af[8];
        #pragma unroll
        for (int ks = 0; ks < 8; ++ks) {
            float4 x0 = *(const float4*)&qs[am][ks * 32 + ak];
            float4 x1 = *(const float4*)&qs[am][ks * 32 + ak + 4];
            af[ks] = pack8(x0, x1);
        }
        #pragma unroll
        for (int pp = 0; pp < 4; ++pp) {
            #pragma unroll
            for (int qt = 0; qt < 2; ++qt) {
                int tp = pp * 16 + 2 * w + qt;
                f32x4 acc = {0.f, 0.f, 0.f, 0.f};
                const u16* bp = wih_bf + (size_t)tp * 4096 + l * 8;
                #pragma unroll
                for (int ks = 0; ks < 8; ++ks) {
                    s16x8 bf = *(const s16x8*)(bp + ks * 512);
                    acc = __builtin_amdgcn_mfma_f32_16x16x32_bf16(af[ks], bf, acc, 0, 0, 0);
                }
                base[pp][qt] = acc;
            }
        }
    }
    // + biases
    #pragma unroll
    for (int pp = 0; pp < 4; ++pp) {
        #pragma unroll
        for (int qt = 0; qt < 2; ++qt) {
            int q = w * 32 + qt * 16 + (l & 15);
            float bsv = b_ih[pp * 512 + q] + b_hh[pp * 512 + q];
            base[pp][qt].x += bsv; base[pp][qt].y += bsv;
            base[pp][qt].z += bsv; base[pp][qt].w += bsv;
        }
    }

    // step 0 (h_r = 0, c = 0): gates = base only
    float c[2][4];
    #pragma unroll
    for (int qt = 0; qt < 2; ++qt) {
        int q = w * 32 + qt * 16 + (l & 15);
        #pragma unroll
        for (int reg = 0; reg < 4; ++reg) {
            int m = (l >> 4) * 4 + reg;
            float gi = base[0][qt][reg];
            float gg = base[2][qt][reg];
            float go = base[3][qt][reg];
            float cc = sigmoidf_(gi) * tanhf(gg);
            c[qt][reg] = cc;
            hq[m][q] = qs[m][q] + sigmoidf_(go) * tanhf(cc);
        }
    }
    __syncthreads();

    // steps 1..3: gates = base + [h,s] @ W_hh_live^T (K=512)
    for (int st = 1; st < 4; ++st) {
        s16x8 af[16];
        #pragma unroll
        for (int ks = 0; ks < 16; ++ks) {
            float4 x0 = *(const float4*)&hq[am][ks * 32 + ak];
            float4 x1 = *(const float4*)&hq[am][ks * 32 + ak + 4];
            af[ks] = pack8(x0, x1);
        }
        __syncthreads();   // all reads done before epilogue writes

        f32x4 gacc[4][2];
        #pragma unroll
        for (int pp = 0; pp < 4; ++pp) {
            #pragma unroll
            for (int qt = 0; qt < 2; ++qt) {
                int tp = pp * 16 + 2 * w + qt;
                f32x4 acc = base[pp][qt];
                const u16* bp = whh_bf + (size_t)tp * 8192 + l * 8;
                #pragma unroll
                for (int ks = 0; ks < 16; ++ks) {
                    s16x8 bf = *(const s16x8*)(bp + ks * 512);
                    acc = __builtin_amdgcn_mfma_f32_16x16x32_bf16(af[ks], bf, acc, 0, 0, 0);
                }
                gacc[pp][qt] = acc;
            }
        }
        #pragma unroll
        for (int qt = 0; qt < 2; ++qt) {
            int q = w * 32 + qt * 16 + (l & 15);
            #pragma unroll
            for (int reg = 0; reg < 4; ++reg) {
                int m = (l >> 4) * 4 + reg;
                float gi = gacc[0][qt][reg];
                float gf = gacc[1][qt][reg];
                float gg = gacc[2][qt][reg];
                float go = gacc[3][qt][reg];
                float cc = sigmoidf_(gf) * c[qt][reg] + sigmoidf_(gi) * tanhf(gg);
                c[qt][reg] = cc;
                hq[m][q] = qs[m][q] + sigmoidf_(go) * tanhf(cc);
            }
        }
        __syncthreads();
    }

    // final: out[n] = dot(h3[n], s); wave w handles samples 2w, 2w+1
    for (int j = 0; j < 2; ++j) {
        int m = w * 2 + j;
        float part = 0.f;
        #pragma unroll
        for (int i = 0; i < 4; ++i) {
            int e = l + 64 * i;
            part += hq[m][e] * hq[m][256 + e];
        }
        for (int off = 32; off; off >>= 1) part += __shfl_xor(part, off, 64);
        if (l == 0) out[n0 + m] = part;
    }
}

// ---------------------------------------------------------------------------
extern "C" void kernel_launch(void* const* d_in, const int* in_sizes, int n_in,
                              void* d_out, int out_size, void* d_ws, size_t ws_size,
                              hipStream_t stream)
{
    const int*   qlc  = (const int*)d_in[0];
    const int*   qrc  = (const int*)d_in[1];
    const int*   slc  = (const int*)d_in[2];
    const int*   src_ = (const int*)d_in[3];
    // d_in[4..7]: degrees — unused by the reference
    const float* emb   = (const float*)d_in[8];
    const float* gcnW  = (const float*)d_in[9];
    const float* gcnwb = (const float*)d_in[10];
    const float* gcnb  = (const float*)d_in[11];
    const float* p1W   = (const float*)d_in[12];
    const float* p1b   = (const float*)d_in[13];
    const float* p2W   = (const float*)d_in[14];
    const float* p2b   = (const float*)d_in[15];
    const float* lng   = (const float*)d_in[16];
    const float* lnb   = (const float*)d_in[17];
    const float* W_ih  = (const float*)d_in[18];
    const float* W_hh  = (const float*)d_in[19];
    const float* b_ih  = (const float*)d_in[20];
    const float* b_hh  = (const float*)d_in[21];
    float* out = (float*)d_out;

    // Workspace layout
    char* ws = (char*)d_ws;
    float* qn      = (float*)(ws + 0);         // 1048576
    float* sn      = (float*)(ws + 1048576);   // 5120
    float* query_g = (float*)(ws + 1053696);   // 1048576
    float* sup_ln  = (float*)(ws + 2102272);   // 5120
    u16*   wih_bf  = (u16*)(ws + 2107392);     // 524288
    u16*   whh_bf  = (u16*)(ws + 2631680);     // 1048576 (full K=512)
    u16*   p1_bf   = (u16*)(ws + 3680256);     // 262144
    u16*   p2_bf   = (u16*)(ws + 3942400);     // 262144
    u16*   emb_bf  = (u16*)(ws + 4204544);     // 51200256 -> total 55404800
    (void)in_sizes; (void)n_in; (void)out_size;

    bool have_emb = ws_size >= (size_t)4204544 + (size_t)EMB_ELEMS * 2;
    int grid_conv = 512 + (have_emb ? EMB_BLOCKS : 0);

    convert_all_kernel<<<grid_conv, 256, 0, stream>>>(
        W_ih, W_hh, p1W, p2W, emb, wih_bf, whh_bf, p1_bf, p2_bf, emb_bf);
    if (have_emb)
        neighbor_kernel<true><<<2 * BQ + 2 * FEW, 256, 0, stream>>>(
            qlc, qrc, slc, src_, emb, emb_bf, gcnW, gcnwb, gcnb, qn, sn);
    else
        neighbor_kernel<false><<<2 * BQ + 2 * FEW, 256, 0, stream>>>(
            qlc, qrc, slc, src_, emb, emb_bf, gcnW, gcnwb, gcnb, qn, sn);
    support_enc_kernel<<<(BQ + FEW + 15) / 16, 512, 0, stream>>>(
        qn, sn, p1_bf, p1b, p2_bf, p2b, lng, lnb, query_g, sup_ln);
    lstm_mfma_kernel<<<BQ / 16, 512, 0, stream>>>(
        query_g, sup_ln, wih_bf, whh_bf, b_ih, b_hh, out);
}

// Round 7
// 341.884 us; speedup vs baseline: 1.2383x; 1.2383x over previous
//
#include <hip/hip_runtime.h>
#include <math.h>

// Problem constants
#define EMBED   128
#define DMODEL  256   // 2*EMBED
#define DINNER  512
#define HIDN    512
#define NBK     200
#define BQ      1024
#define FEW     5
#define PAD_IDX 200000
#define LN_EPS  1e-5f
#define NTILES  7
#define MPAD    1056   // padded support-encoder row count (1029 -> 33*32)

#define EMB_ELEMS 25600128   // 200001 * 128
#define EMB_THREADS (EMB_ELEMS / 8)
#define EMB_BLOCKS ((EMB_THREADS + 255) / 256)

typedef short          s16x8  __attribute__((ext_vector_type(8)));
typedef float          f32x4  __attribute__((ext_vector_type(4)));
typedef float          f32x16 __attribute__((ext_vector_type(16)));
typedef unsigned int   u32;
typedef unsigned short u16;

__device__ __forceinline__ float sigmoidf_(float x) { return 1.0f / (1.0f + expf(-x)); }

// float -> bf16 (round-to-nearest-even), raw u16
__device__ __forceinline__ u32 f2bf(float f) {
    u32 u = __builtin_bit_cast(u32, f);
    u += 0x7fffu + ((u >> 16) & 1u);
    return u >> 16;
}
__device__ __forceinline__ s16x8 pack8(float4 a, float4 b) {
    typedef u32 u32x4_ __attribute__((ext_vector_type(4)));
    u32x4_ q;
    q.x = f2bf(a.x) | (f2bf(a.y) << 16);
    q.y = f2bf(a.z) | (f2bf(a.w) << 16);
    q.z = f2bf(b.x) | (f2bf(b.y) << 16);
    q.w = f2bf(b.z) | (f2bf(b.w) << 16);
    return __builtin_bit_cast(s16x8, q);
}

// ---------------------------------------------------------------------------
// Kernel 0: conversion. Blocks [0,384): weights -> bf16 MFMA-B-fragment order
// (wih live rows K=256, whh live rows K=256 (cols 0..255), p1W, p2W).
// Blocks [384,+N): emb fp32 -> bf16. Frag layout for [N x K] (y = x @ W^T):
// element (n,k) at flat = ((tile*KS + ks)*64 + lane)*8 + j,
// n = tile*16+(lane&15), k = ks*32+(lane>>4)*8+j, KS = K/32.
// ---------------------------------------------------------------------------
__global__ __launch_bounds__(256) void convert_all_kernel(
    const float* __restrict__ W_ih, const float* __restrict__ W_hh,
    const float* __restrict__ p1W,  const float* __restrict__ p2W,
    const float* __restrict__ emb,
    u16* __restrict__ wih_bf, u16* __restrict__ whh_bf,
    u16* __restrict__ p1_bf,  u16* __restrict__ p2_bf,
    u16* __restrict__ emb_bf)
{
    int bid = blockIdx.x;
    if (bid >= 384) {
        size_t gid = (size_t)(bid - 384) * 256 + threadIdx.x;
        if (gid < EMB_THREADS) {
            size_t base = gid * 8;
            float4 x0 = *(const float4*)(emb + base);
            float4 x1 = *(const float4*)(emb + base + 4);
            *(s16x8*)(emb_bf + base) = pack8(x0, x1);
        }
        return;
    }
    int gid = bid * 256 + threadIdx.x;              // 0..98303
    const float* src; u16* dst; int local, stride, KS, liveRemap;
    if (gid < 32768)      { local = gid;          src = W_ih; dst = wih_bf; stride = 256; KS = 8;  liveRemap = 1; }
    else if (gid < 65536) { local = gid - 32768;  src = W_hh; dst = whh_bf; stride = 512; KS = 8;  liveRemap = 1; }
    else if (gid < 81920) { local = gid - 65536;  src = p1W;  dst = p1_bf;  stride = 256; KS = 8;  liveRemap = 0; }
    else                  { local = gid - 81920;  src = p2W;  dst = p2_bf;  stride = 512; KS = 16; liveRemap = 0; }
    int lane = local & 63;
    int ts   = local >> 6;
    int ks   = ts & (KS - 1);
    int tile = ts / KS;
    int n  = tile * 16 + (lane & 15);
    int kb = ks * 32 + (lane >> 4) * 8;
    int row = liveRemap ? ((n >> 8) * 512 + (n & 255)) : n;
    const float* sp = src + (size_t)row * stride + kb;
    float4 x0 = *(const float4*)sp;
    float4 x1 = *(const float4*)(sp + 4);
    *(s16x8*)(dst + (size_t)local * 8) = pack8(x0, x1);
}

// ---------------------------------------------------------------------------
// Kernel 1: neighbor encoder (r6 structure): MFMA bf16 32x32x16, cooperative
// bf16 LDS staging (1024 x 16B requests per tile), XOR-swizzled chunks,
// 2-deep gather pipeline.
// ---------------------------------------------------------------------------
template<bool BF>
__global__ __launch_bounds__(256) void neighbor_kernel(
    const int* __restrict__ qlc, const int* __restrict__ qrc,
    const int* __restrict__ slc, const int* __restrict__ src_,
    const float* __restrict__ emb, const u16* __restrict__ emb_bf,
    const float* __restrict__ W,
    const float* __restrict__ wb,  const float* __restrict__ bb,
    float* __restrict__ qn, float* __restrict__ sn)
{
    int b = blockIdx.x;
    const int* conn; float* out; int n; int side;
    if (b < BQ)                { conn = qlc;  n = b;            side = 0; out = qn; }
    else if (b < 2*BQ)         { conn = qrc;  n = b - BQ;       side = 1; out = qn; }
    else if (b < 2*BQ + FEW)   { conn = slc;  n = b - 2*BQ;     side = 0; out = sn; }
    else                       { conn = src_; n = b - 2*BQ-FEW; side = 1; out = sn; }

    int t = threadIdx.x;
    int w = t >> 6, l = t & 63;
    int d0 = w * 32;
    int m31 = l & 31, half = l >> 5;

    __shared__ __align__(16) u16 bs[64 * 128];   // 16 KB

    s16x8 afrag[16];
    const float* wrow = W + (d0 + m31) * DMODEL + half * 8;
    #pragma unroll
    for (int ks = 0; ks < 16; ++ks) {
        float4 x0 = *(const float4*)(wrow + ks * 16);
        float4 x1 = *(const float4*)(wrow + ks * 16 + 4);
        afrag[ks] = pack8(x0, x1);
    }

    const int2* crow = (const int2*)(conn + n * NBK * 2);
    u32 vmask = 0;
    #pragma unroll
    for (int nt = 0; nt < NTILES; ++nt) {
        int krow = nt * 32 + m31;
        if (krow < NBK) {
            int2 re = crow[krow];
            if (re.x != PAD_IDX && re.y != PAD_IDX) vmask |= (1u << nt);
        }
    }

    int gr = t >> 2, gq = t & 3;
    int g_m = gr & 31, g_is_ent = gr >> 5;
    int gsrc[NTILES];
    #pragma unroll
    for (int nt = 0; nt < NTILES; ++nt) {
        int krow = nt * 32 + g_m;
        int rel = PAD_IDX, ent = PAD_IDX;
        if (krow < NBK) { int2 re = crow[krow]; rel = re.x; ent = re.y; }
        int v = (rel != PAD_IDX) && (ent != PAD_IDX);
        gsrc[nt] = v ? (g_is_ent ? ent : rel) : PAD_IDX;
    }

    int tl[NTILES]; int ntl = 0;
    #pragma unroll
    for (int nt = 0; nt < NTILES; ++nt)
        if (__any((int)((vmask >> nt) & 1u))) tl[ntl++] = nt;

    float vm[16];
    #pragma unroll
    for (int r = 0; r < 16; ++r) vm[r] = -INFINITY;

    int swl = gr * 128;
    int rsw_rel = m31 * 128;
    int rsw_ent = (32 + m31) * 128;
    int rx = m31 & 15;

    s16x8 stg[4];
    auto load_tile = [&](int nt, s16x8* dstv) {
        if (BF) {
            const u16* p = emb_bf + (size_t)gsrc[nt] * EMBED + gq * 32;
            #pragma unroll
            for (int i = 0; i < 4; ++i) dstv[i] = *(const s16x8*)(p + i * 8);
        } else {
            const float* p = emb + (size_t)gsrc[nt] * EMBED + gq * 32;
            #pragma unroll
            for (int i = 0; i < 4; ++i)
                dstv[i] = pack8(*(const float4*)(p + i * 8), *(const float4*)(p + i * 8 + 4));
        }
    };

    if (ntl > 0) load_tile(tl[0], stg);

    for (int i = 0; i < ntl; ++i) {
        int nt = tl[i];
        __syncthreads();
        #pragma unroll
        for (int j = 0; j < 4; ++j) {
            int c = gq * 4 + j;
            *(s16x8*)(bs + swl + ((c ^ (gr & 15)) * 8)) = stg[j];
        }
        __syncthreads();

        s16x8 stg2[4];
        if (i + 1 < ntl) load_tile(tl[i + 1], stg2);

        f32x16 acc = {0.f,0.f,0.f,0.f,0.f,0.f,0.f,0.f,0.f,0.f,0.f,0.f,0.f,0.f,0.f,0.f};
        #pragma unroll
        for (int ks = 0; ks < 8; ++ks) {
            int c = ks * 2 + half;
            s16x8 bfr = *(const s16x8*)(bs + rsw_rel + ((c ^ rx) * 8));
            acc = __builtin_amdgcn_mfma_f32_32x32x16_bf16(afrag[ks], bfr, acc, 0, 0, 0);
        }
        #pragma unroll
        for (int ks = 0; ks < 8; ++ks) {
            int c = ks * 2 + half;
            s16x8 bfr = *(const s16x8*)(bs + rsw_ent + ((c ^ rx) * 8));
            acc = __builtin_amdgcn_mfma_f32_32x32x16_bf16(afrag[8 + ks], bfr, acc, 0, 0, 0);
        }
        int cv = (vmask >> nt) & 1;
        #pragma unroll
        for (int r = 0; r < 16; ++r) {
            float v = cv ? acc[r] : -INFINITY;
            vm[r] = fmaxf(vm[r], v);
        }
        #pragma unroll
        for (int j = 0; j < 4; ++j) stg[j] = stg2[j];
    }

    #pragma unroll
    for (int off = 1; off < 32; off <<= 1) {
        #pragma unroll
        for (int r = 0; r < 16; ++r)
            vm[r] = fmaxf(vm[r], __shfl_xor(vm[r], off, 64));
    }

    if (m31 == 0) {
        #pragma unroll
        for (int r = 0; r < 16; ++r) {
            int d = d0 + (r & 3) + 8 * (r >> 2) + 4 * half;
            float p = vm[r] + wb[d] + bb[d];
            p = (p >= 0.f) ? p : 0.1f * p;
            out[n * DMODEL + side * EMBED + d] = tanhf(p);
        }
    }
}

// Guarded x-row pointer for support encoder (rows: 0..1023 qn, 1024..1028 sn)
__device__ __forceinline__ const float* xrow_ptr(
    const float* qn, const float* sn, int row) {
    if (row < BQ) return qn + (size_t)row * DMODEL;
    if (row < BQ + FEW) return sn + (size_t)(row - BQ) * DMODEL;
    return nullptr;
}

// ---------------------------------------------------------------------------
// Kernel 2a: support GEMM1: h1 = relu(X @ p1W^T + p1b), X (1029x256 padded
// to 1056), out bf16 row-major (1056x512). Grid 33x8 = 264 blocks;
// block tile M=32, N=64. B per block = 32 KB.
// ---------------------------------------------------------------------------
__global__ __launch_bounds__(256) void gemm1_kernel(
    const float* __restrict__ qn, const float* __restrict__ sn,
    const u16* __restrict__ p1_bf, const float* __restrict__ p1b,
    u16* __restrict__ h1_bf)
{
    int bid = blockIdx.x;
    int mb = bid % 33, nb = bid / 33;
    int m0 = mb * 32, n0 = nb * 64;
    int t = threadIdx.x, w = t >> 6, l = t & 63;
    int msub = w & 1, npair = w >> 1;
    int am = l & 15, ak = (l >> 4) * 8;

    int arow = m0 + msub * 16 + am;
    const float* xr = xrow_ptr(qn, sn, arow);
    s16x8 af[8];
    #pragma unroll
    for (int ks = 0; ks < 8; ++ks) {
        float4 x0 = {0.f,0.f,0.f,0.f}, x1 = {0.f,0.f,0.f,0.f};
        if (xr) { x0 = *(const float4*)(xr + ks * 32 + ak); x1 = *(const float4*)(xr + ks * 32 + ak + 4); }
        af[ks] = pack8(x0, x1);
    }

    #pragma unroll
    for (int j = 0; j < 2; ++j) {
        int nt = (n0 >> 4) + npair * 2 + j;
        f32x4 acc = {0.f, 0.f, 0.f, 0.f};
        const u16* bp = p1_bf + (size_t)nt * 4096 + l * 8;
        #pragma unroll
        for (int ks = 0; ks < 8; ++ks) {
            s16x8 bf = *(const s16x8*)(bp + ks * 512);
            acc = __builtin_amdgcn_mfma_f32_16x16x32_bf16(af[ks], bf, acc, 0, 0, 0);
        }
        int nn = nt * 16 + (l & 15);
        float bj = p1b[nn];
        #pragma unroll
        for (int reg = 0; reg < 4; ++reg) {
            int mg = m0 + msub * 16 + (l >> 4) * 4 + reg;
            float v = fmaxf(acc[reg] + bj, 0.f);
            h1_bf[(size_t)mg * DINNER + nn] = (u16)f2bf(v);
        }
    }
}

// ---------------------------------------------------------------------------
// Kernel 2b: support GEMM2: o = h1 @ p2W^T + p2b + x (residual), f32 out
// (1056x256). Grid 33x4 = 132 blocks; tile M=32, N=64, K=512. B = 64 KB.
// ---------------------------------------------------------------------------
__global__ __launch_bounds__(256) void gemm2_kernel(
    const u16* __restrict__ h1_bf, const u16* __restrict__ p2_bf,
    const float* __restrict__ p2b, const float* __restrict__ qn,
    const float* __restrict__ sn, float* __restrict__ o_g)
{
    int bid = blockIdx.x;
    int mb = bid % 33, nb = bid / 33;
    int m0 = mb * 32, n0 = nb * 64;
    int t = threadIdx.x, w = t >> 6, l = t & 63;
    int msub = w & 1, npair = w >> 1;
    int am = l & 15, ak = (l >> 4) * 8;

    int arow = m0 + msub * 16 + am;
    s16x8 af[16];
    #pragma unroll
    for (int ks = 0; ks < 16; ++ks)
        af[ks] = *(const s16x8*)(h1_bf + (size_t)arow * DINNER + ks * 32 + ak);

    #pragma unroll
    for (int j = 0; j < 2; ++j) {
        int nt = (n0 >> 4) + npair * 2 + j;
        f32x4 acc = {0.f, 0.f, 0.f, 0.f};
        const u16* bp = p2_bf + (size_t)nt * 8192 + l * 8;
        #pragma unroll
        for (int ks = 0; ks < 16; ++ks) {
            s16x8 bf = *(const s16x8*)(bp + ks * 512);
            acc = __builtin_amdgcn_mfma_f32_16x16x32_bf16(af[ks], bf, acc, 0, 0, 0);
        }
        int nn = nt * 16 + (l & 15);
        float bj = p2b[nn];
        #pragma unroll
        for (int reg = 0; reg < 4; ++reg) {
            int mg = m0 + msub * 16 + (l >> 4) * 4 + reg;
            const float* xr = xrow_ptr(qn, sn, mg);
            float res = xr ? xr[nn] : 0.f;
            o_g[(size_t)mg * DMODEL + nn] = acc[reg] + bj + res;
        }
    }
}

// ---------------------------------------------------------------------------
// Kernel 2c: LayerNorm rows 0..1028 of o_g -> query_g / sup_ln.
// Grid 258 blocks x 4 rows (one wave per row).
// ---------------------------------------------------------------------------
__global__ __launch_bounds__(256) void ln_kernel(
    const float* __restrict__ o_g, const float* __restrict__ lng,
    const float* __restrict__ lnb, float* __restrict__ query_g,
    float* __restrict__ sup_ln)
{
    int t = threadIdx.x, w = t >> 6, l = t & 63;
    int row = blockIdx.x * 4 + w;
    if (row >= BQ + FEW) return;
    const float* op = o_g + (size_t)row * DMODEL;
    float v[4], sum = 0.f, sq = 0.f;
    #pragma unroll
    for (int i = 0; i < 4; ++i) {
        v[i] = op[l + 64 * i];
        sum += v[i]; sq += v[i] * v[i];
    }
    for (int off = 32; off; off >>= 1) {
        sum += __shfl_xor(sum, off, 64);
        sq  += __shfl_xor(sq,  off, 64);
    }
    float mu  = sum * (1.f / DMODEL);
    float var = sq * (1.f / DMODEL) - mu * mu;
    float inv = rsqrtf(var + LN_EPS);
    float* outp = (row < BQ) ? (query_g + (size_t)row * DMODEL)
                             : (sup_ln + (size_t)(row - BQ) * DMODEL);
    #pragma unroll
    for (int i = 0; i < 4; ++i) {
        int dd = l + 64 * i;
        outp[dd] = (v[i] - mu) * inv * lng[dd] + lnb[dd];
    }
}

// ---------------------------------------------------------------------------
// Kernel 3: sWp[p] = s . W_hh[row(p), 256:512]; also writes s_vec.
// s = mean of the 5 LN'd support rows. 64 blocks x 4 waves x 4 outputs.
// ---------------------------------------------------------------------------
__global__ __launch_bounds__(256) void sWp_kernel(
    const float* __restrict__ sup_ln, const float* __restrict__ W_hh,
    float* __restrict__ sWp, float* __restrict__ s_vec)
{
    int w = threadIdx.x >> 6, l = threadIdx.x & 63;
    int wave_id = blockIdx.x * 4 + w;   // 0..255
    float se[4];
    #pragma unroll
    for (int j = 0; j < 4; ++j) {
        float a = 0.f;
        for (int i = 0; i < FEW; ++i) a += sup_ln[i * DMODEL + l + 64 * j];
        se[j] = a * (1.f / FEW);
    }
    if (blockIdx.x == 0 && w == 0) {
        #pragma unroll
        for (int j = 0; j < 4; ++j) s_vec[l + 64 * j] = se[j];
    }
    for (int i = 0; i < 4; ++i) {
        int p = wave_id * 4 + i;        // 0..1023
        int pp = p >> 8, q = p & 255;
        const float* wr = W_hh + (size_t)(pp * 512 + q) * HIDN + 256;
        float part = 0.f;
        #pragma unroll
        for (int j = 0; j < 4; ++j) part += se[j] * wr[l + 64 * j];
        for (int off = 32; off; off >>= 1) part += __shfl_xor(part, off, 64);
        if (l == 0) sWp[p] = part;
    }
}

// ---------------------------------------------------------------------------
// Kernel 4a: base gates GEMM: base_g[m][p] = query_g[m] . W_ih_live[p] +
// b_ih[p] + b_hh[p]  (p = pp*256+q live index). M=1024, N=1024, K=256.
// Grid 32x16 = 512 blocks; tile M=32, N=64.
// ---------------------------------------------------------------------------
__global__ __launch_bounds__(256) void base_kernel(
    const float* __restrict__ query_g, const u16* __restrict__ wih_bf,
    const float* __restrict__ b_ih, const float* __restrict__ b_hh,
    float* __restrict__ base_g)
{
    int bid = blockIdx.x;
    int mb = bid & 31, nb = bid >> 5;
    int m0 = mb * 32, n0 = nb * 64;
    int t = threadIdx.x, w = t >> 6, l = t & 63;
    int msub = w & 1, npair = w >> 1;
    int am = l & 15, ak = (l >> 4) * 8;

    int arow = m0 + msub * 16 + am;
    const float* xr = query_g + (size_t)arow * DMODEL;
    s16x8 af[8];
    #pragma unroll
    for (int ks = 0; ks < 8; ++ks)
        af[ks] = pack8(*(const float4*)(xr + ks * 32 + ak),
                       *(const float4*)(xr + ks * 32 + ak + 4));

    #pragma unroll
    for (int j = 0; j < 2; ++j) {
        int nt = (n0 >> 4) + npair * 2 + j;
        f32x4 acc = {0.f, 0.f, 0.f, 0.f};
        const u16* bp = wih_bf + (size_t)nt * 4096 + l * 8;
        #pragma unroll
        for (int ks = 0; ks < 8; ++ks) {
            s16x8 bf = *(const s16x8*)(bp + ks * 512);
            acc = __builtin_amdgcn_mfma_f32_16x16x32_bf16(af[ks], bf, acc, 0, 0, 0);
        }
        int p = nt * 16 + (l & 15);
        int pp = p >> 8, q = p & 255;
        float bsv = b_ih[pp * 512 + q] + b_hh[pp * 512 + q];
        #pragma unroll
        for (int reg = 0; reg < 4; ++reg) {
            int mg = m0 + msub * 16 + (l >> 4) * 4 + reg;
            base_g[(size_t)mg * 1024 + p] = acc[reg] + bsv;
        }
    }
}

// ---------------------------------------------------------------------------
// Kernel 4b: LSTM step 0 (h_r = 0, c = 0), elementwise on base_g.
// Grid 1024 blocks (one sample each) x 256 threads (one q each).
// ---------------------------------------------------------------------------
__global__ __launch_bounds__(256) void step0_kernel(
    const float* __restrict__ base_g, const float* __restrict__ query_g,
    float* __restrict__ c_g, float* __restrict__ h_out)
{
    int m = blockIdx.x, q = threadIdx.x;
    const float* bm = base_g + (size_t)m * 1024;
    float gi = bm[q];
    float gg = bm[512 + q];
    float go = bm[768 + q];
    float cc = sigmoidf_(gi) * tanhf(gg);
    c_g[(size_t)m * DMODEL + q] = cc;
    h_out[(size_t)m * DMODEL + q] = query_g[(size_t)m * DMODEL + q]
                                  + sigmoidf_(go) * tanhf(cc);
}

// ---------------------------------------------------------------------------
// Kernel 4c: LSTM step (st>=1): gates = base + sWp + h_prev @ W_hh_live^T
// (K=256), then c/h update. Grid 32x8 = 256 blocks; block = 32 samples x
// 32 q-cols x 4 gates; wave = 16x16 patch x 4 gates. c in-place (per-(m,q)
// ownership is stable across steps); h ping-pongs between two buffers.
// ---------------------------------------------------------------------------
__global__ __launch_bounds__(256) void step_kernel(
    const float* __restrict__ h_prev, const float* __restrict__ base_g,
    const float* __restrict__ sWp, const u16* __restrict__ whh_bf,
    const float* __restrict__ query_g, float* __restrict__ c_g,
    float* __restrict__ h_next)
{
    int bid = blockIdx.x;
    int mb = bid & 31, qb = bid >> 5;
    int m0 = mb * 32, q0 = qb * 32;
    int t = threadIdx.x, w = t >> 6, l = t & 63;
    int msub = w & 1, qsub = w >> 1;
    int am = l & 15, ak = (l >> 4) * 8;

    int arow = m0 + msub * 16 + am;
    const float* hr = h_prev + (size_t)arow * DMODEL;
    s16x8 af[8];
    #pragma unroll
    for (int ks = 0; ks < 8; ++ks)
        af[ks] = pack8(*(const float4*)(hr + ks * 32 + ak),
                       *(const float4*)(hr + ks * 32 + ak + 4));

    int qq = q0 + qsub * 16 + (l & 15);
    f32x4 gacc[4];
    #pragma unroll
    for (int pp = 0; pp < 4; ++pp) {
        int tp = pp * 16 + qb * 2 + qsub;
        float sw = sWp[pp * 256 + qq];
        f32x4 acc;
        #pragma unroll
        for (int reg = 0; reg < 4; ++reg) {
            int mg = m0 + msub * 16 + (l >> 4) * 4 + reg;
            acc[reg] = base_g[(size_t)mg * 1024 + pp * 256 + qq] + sw;
        }
        const u16* bp = whh_bf + (size_t)tp * 4096 + l * 8;
        #pragma unroll
        for (int ks = 0; ks < 8; ++ks) {
            s16x8 bf = *(const s16x8*)(bp + ks * 512);
            acc = __builtin_amdgcn_mfma_f32_16x16x32_bf16(af[ks], bf, acc, 0, 0, 0);
        }
        gacc[pp] = acc;
    }

    #pragma unroll
    for (int reg = 0; reg < 4; ++reg) {
        int mg = m0 + msub * 16 + (l >> 4) * 4 + reg;
        float gi = gacc[0][reg];
        float gf = gacc[1][reg];
        float gg = gacc[2][reg];
        float go = gacc[3][reg];
        size_t idx = (size_t)mg * DMODEL + qq;
        float cold = c_g[idx];
        float cc = sigmoidf_(gf) * cold + sigmoidf_(gi) * tanhf(gg);
        c_g[idx] = cc;
        h_next[idx] = query_g[idx] + sigmoidf_(go) * tanhf(cc);
    }
}

// ---------------------------------------------------------------------------
// Kernel 5: out[n] = dot(h_final[n], s_vec). 16 blocks x 4 waves x 16 samples.
// ---------------------------------------------------------------------------
__global__ __launch_bounds__(256) void final_kernel(
    const float* __restrict__ h_st, const float* __restrict__ s_vec,
    float* __restrict__ out)
{
    int w = threadIdx.x >> 6, l = threadIdx.x & 63;
    int wave_id = blockIdx.x * 4 + w;
    for (int i = 0; i < 16; ++i) {
        int n = wave_id * 16 + i;
        float part = 0.f;
        #pragma unroll
        for (int j = 0; j < 4; ++j) {
            int e = l + 64 * j;
            part += h_st[(size_t)n * DMODEL + e] * s_vec[e];
        }
        for (int off = 32; off; off >>= 1) part += __shfl_xor(part, off, 64);
        if (l == 0) out[n] = part;
    }
}

// ---------------------------------------------------------------------------
extern "C" void kernel_launch(void* const* d_in, const int* in_sizes, int n_in,
                              void* d_out, int out_size, void* d_ws, size_t ws_size,
                              hipStream_t stream)
{
    const int*   qlc  = (const int*)d_in[0];
    const int*   qrc  = (const int*)d_in[1];
    const int*   slc  = (const int*)d_in[2];
    const int*   src_ = (const int*)d_in[3];
    // d_in[4..7]: degrees — unused by the reference
    const float* emb   = (const float*)d_in[8];
    const float* gcnW  = (const float*)d_in[9];
    const float* gcnwb = (const float*)d_in[10];
    const float* gcnb  = (const float*)d_in[11];
    const float* p1W   = (const float*)d_in[12];
    const float* p1b   = (const float*)d_in[13];
    const float* p2W   = (const float*)d_in[14];
    const float* p2b   = (const float*)d_in[15];
    const float* lng   = (const float*)d_in[16];
    const float* lnb   = (const float*)d_in[17];
    const float* W_ih  = (const float*)d_in[18];
    const float* W_hh  = (const float*)d_in[19];
    const float* b_ih  = (const float*)d_in[20];
    const float* b_hh  = (const float*)d_in[21];
    float* out = (float*)d_out;

    // Workspace layout (bytes)
    char* ws = (char*)d_ws;
    float* qn      = (float*)(ws + 0);          // 1048576
    float* sn      = (float*)(ws + 1048576);    // 5120
    float* query_g = (float*)(ws + 1053696);    // 1048576
    float* sup_ln  = (float*)(ws + 2102272);    // 5120
    float* s_vec   = (float*)(ws + 2107392);    // 1024
    float* sWp     = (float*)(ws + 2108416);    // 4096
    u16*   wih_bf  = (u16*)(ws + 2112512);      // 524288
    u16*   whh_bf  = (u16*)(ws + 2636800);      // 524288
    u16*   p1_bf   = (u16*)(ws + 3161088);      // 262144
    u16*   p2_bf   = (u16*)(ws + 3423232);      // 262144
    u16*   h1_bf   = (u16*)(ws + 3685376);      // 1081344 (1056x512 bf16)
    float* o_g     = (float*)(ws + 4766720);    // 1081344 (1056x256 f32)
    float* base_g  = (float*)(ws + 5848064);    // 4194304 (1024x1024 f32)
    float* c_g     = (float*)(ws + 10042368);   // 1048576
    float* h_a     = (float*)(ws + 11090944);   // 1048576
    float* h_b     = (float*)(ws + 12139520);   // 1048576
    u16*   emb_bf  = (u16*)(ws + 13188096);     // 51200256 -> total 64388352
    (void)in_sizes; (void)n_in; (void)out_size;

    bool have_emb = ws_size >= (size_t)13188096 + (size_t)EMB_ELEMS * 2;
    int grid_conv = 384 + (have_emb ? EMB_BLOCKS : 0);

    convert_all_kernel<<<grid_conv, 256, 0, stream>>>(
        W_ih, W_hh, p1W, p2W, emb, wih_bf, whh_bf, p1_bf, p2_bf, emb_bf);
    if (have_emb)
        neighbor_kernel<true><<<2 * BQ + 2 * FEW, 256, 0, stream>>>(
            qlc, qrc, slc, src_, emb, emb_bf, gcnW, gcnwb, gcnb, qn, sn);
    else
        neighbor_kernel<false><<<2 * BQ + 2 * FEW, 256, 0, stream>>>(
            qlc, qrc, slc, src_, emb, emb_bf, gcnW, gcnwb, gcnb, qn, sn);

    gemm1_kernel<<<33 * 8, 256, 0, stream>>>(qn, sn, p1_bf, p1b, h1_bf);
    gemm2_kernel<<<33 * 4, 256, 0, stream>>>(h1_bf, p2_bf, p2b, qn, sn, o_g);
    ln_kernel<<<258, 256, 0, stream>>>(o_g, lng, lnb, query_g, sup_ln);
    sWp_kernel<<<64, 256, 0, stream>>>(sup_ln, W_hh, sWp, s_vec);

    base_kernel<<<512, 256, 0, stream>>>(query_g, wih_bf, b_ih, b_hh, base_g);
    step0_kernel<<<1024, 256, 0, stream>>>(base_g, query_g, c_g, h_a);
    step_kernel<<<256, 256, 0, stream>>>(h_a, base_g, sWp, whh_bf, query_g, c_g, h_b);
    step_kernel<<<256, 256, 0, stream>>>(h_b, base_g, sWp, whh_bf, query_g, c_g, h_a);
    step_kernel<<<256, 256, 0, stream>>>(h_a, base_g, sWp, whh_bf, query_g, c_g, h_b);
    final_kernel<<<16, 256, 0, stream>>>(h_b, s_vec, out);
}